// Round 9
// baseline (508.623 us; speedup 1.0000x reference)
//
#include <hip/hip_runtime.h>
#include <hip/hip_bf16.h>
#include <math.h>

// N_IN=32, N_OUT=31, H=128, npts=65536.
// Augmented propagation, all 4 layers via MFMA 16x16x32 bf16:
//   L0: Z0 = W0 @ [I_31 | x]  (identity cols = register one-hot B-frags)
//   X_l = [D*Z[:,:31] | tanh(Z[:,31]+b)] ; L3 = W3pad @ X2, direct scatter.
// 512 thr / 8 waves; PB=2 pts/pass, 8 passes; ping-pong XT (4 barriers/pass);
// paired m-tiles in L0/L1/L2: wave (q=w&3, pt=w>>2) does rows {16q..+16,
// 64+16q..+16} -> B-frags shared across the 2 m-tiles (halved LDS reads).
// LDS 44.6KB -> 2 blocks/CU; W1/W2 frags register-resident (64 VGPR),
// W3/biases in LDS to stay under the 128-VGPR / 4-waves-per-SIMD step.

using short8 = __attribute__((ext_vector_type(8))) short;
using f32x4  = __attribute__((ext_vector_type(4))) float;

#define PB 2
#define PPB 16
#define NPASS (PPB / PB)  // 8
#define ST 136            // XT row stride (272 B: 16B-aligned, breaks pow2 banks)
#define ST3 136           // W3L row stride

__device__ __forceinline__ float fast_tanh(float z) {
    float e = __expf(2.0f * z);
    return 1.0f - 2.0f * __builtin_amdgcn_rcpf(e + 1.0f);
}
__device__ __forceinline__ unsigned pk2(float lo, float hi) {
    unsigned r;
    asm("v_cvt_pk_bf16_f32 %0, %1, %2" : "=v"(r) : "v"(lo), "v"(hi));
    return r;
}
__device__ __forceinline__ float bf2f(ushort u) {
    union { unsigned u; float f; } c; c.u = ((unsigned)u) << 16; return c.f;
}
__device__ __forceinline__ ushort f2bf1(float f) {
    union { float f; unsigned u; } v; v.f = f;
    unsigned r = v.u + 0x7fffu + ((v.u >> 16) & 1u);
    return (ushort)(r >> 16);
}
__device__ __forceinline__ short8 pack8f(const float* s) {
    union { unsigned u[4]; short8 v; } r;
    #pragma unroll
    for (int qq = 0; qq < 4; ++qq) r.u[qq] = pk2(s[2 * qq], s[2 * qq + 1]);
    return r.v;
}
__device__ __forceinline__ short8 load_row8(const float* p) {
    float tmp[8];
    const float4* p4 = reinterpret_cast<const float4*>(p);
    float4 q0 = p4[0], q1 = p4[1];
    tmp[0]=q0.x; tmp[1]=q0.y; tmp[2]=q0.z; tmp[3]=q0.w;
    tmp[4]=q1.x; tmp[5]=q1.y; tmp[6]=q1.z; tmp[7]=q1.w;
    return pack8f(tmp);
}

__global__ void __launch_bounds__(512, 2)
node_mfma(const float* __restrict__ tptr,
          const float* __restrict__ y,
          const float* __restrict__ W0, const float* __restrict__ b0,
          const float* __restrict__ W1, const float* __restrict__ b1,
          const float* __restrict__ W2, const float* __restrict__ b2,
          const float* __restrict__ W3, const float* __restrict__ b3,
          float* __restrict__ out, float* __restrict__ jac, int npts) {
    __shared__ __align__(16) ushort XT[2][PB][32][ST];  // 34,816 B
    __shared__ __align__(16) ushort W3L[32 * ST3];      //  8,704 B
    __shared__ __align__(16) ushort bbf[3][128];        //    768 B
    __shared__ __align__(16) ushort b3L[32];            //     64 B
    __shared__ __align__(16) float xb[PB][32];          //    256 B

    const int tid  = threadIdx.x;
    const int w    = tid >> 6;
    const int lane = tid & 63;
    const int r16  = lane & 15;
    const int g    = lane >> 4;
    const int q    = w & 3;    // m-tile pair {q, q+4} for L0/L1/L2
    const int pt   = w >> 2;   // point (0/1) this wave handles
    const int mw   = (w >> 1) & 1, nw = w & 1;  // L3 task (same pt)

    // ---- LDS init: W3 (zero-padded to 32 rows), biases ----
    {
        int row = tid >> 4, ch = tid & 15;
        float tmp[8];
        if (row < 31) {
            const float4* p4 = reinterpret_cast<const float4*>(W3 + row * 128 + ch * 8);
            float4 q0 = p4[0], q1 = p4[1];
            tmp[0]=q0.x; tmp[1]=q0.y; tmp[2]=q0.z; tmp[3]=q0.w;
            tmp[4]=q1.x; tmp[5]=q1.y; tmp[6]=q1.z; tmp[7]=q1.w;
        } else {
            #pragma unroll
            for (int i = 0; i < 8; ++i) tmp[i] = 0.0f;
        }
        *reinterpret_cast<short8*>(&W3L[row * ST3 + ch * 8]) = pack8f(tmp);
    }
    if (tid < 384) {
        int L = tid >> 7, i = tid & 127;
        bbf[L][i] = f2bf1((L == 0 ? b0 : L == 1 ? b1 : b2)[i]);
    }
    if (tid < 32) b3L[tid] = (tid < 31) ? f2bf1(b3[tid]) : (ushort)0;

    // ---- hot weights -> registers ----
    short8 aW0[2];       // W0 A-frags for mt 0/1 (K=32, single kc)
    short8 aW[2][2][4];  // [layer][mt][kc] for W1, W2
    #pragma unroll
    for (int mt = 0; mt < 2; ++mt) {
        const int row = 16 * q + 64 * mt + r16;
        aW0[mt] = load_row8(W0 + row * 32 + g * 8);
        #pragma unroll
        for (int kc = 0; kc < 4; ++kc) {
            aW[0][mt][kc] = load_row8(W1 + row * 128 + kc * 32 + g * 8);
            aW[1][mt][kc] = load_row8(W2 + row * 128 + kc * 32 + g * 8);
        }
    }

    // ---- one-hot B-frags for the identity columns of [I|x] ----
    // B elem i of lane (r16,g) is k = g*8+i; col r16 (bf0) and col 16+r16 (bf1).
    short8 oh0, oh1;
    {
        union { ushort u[8]; short8 v; } z0, z1;
        #pragma unroll
        for (int i = 0; i < 8; ++i) {
            z0.u[i] = (g == (r16 >> 3) && i == (r16 & 7)) ? (ushort)0x3F80 : (ushort)0;
            z1.u[i] = (r16 < 15 && g == ((16 + r16) >> 3) && i == ((16 + r16) & 7))
                          ? (ushort)0x3F80 : (ushort)0;
        }
        oh0 = z0.v; oh1 = z1.v;
    }

    const float force = sinf(tptr[0]);

    // ---- y prefetch for pass 0 ----
    const bool act = tid < PB * 32;   // 64 threads
    const int pl0 = tid >> 5, c0 = tid & 31;
    float pf = 0.0f;
    if (act && c0 < 31) pf = y[(size_t)(blockIdx.x * PPB + pl0) * 31 + c0];

    // ---- shared epilogue: Z cols -> X' (D-scaled cols + tanh col) ----
    auto epi = [&](f32x4 a0, f32x4 a1, int mt, const ushort* bL, ushort* dst) {
        const int row0 = 16 * q + 64 * mt;
        uint2 bq = *reinterpret_cast<const uint2*>(&bL[row0 + 4 * g]);
        const ushort* bqs = reinterpret_cast<const ushort*>(&bq);
        float va[4], vb[4];
        #pragma unroll
        for (int reg = 0; reg < 4; ++reg) {
            float tv = fast_tanh(a1[reg] + bf2f(bqs[reg]));
            float d  = 1.0f - tv * tv;
            float dd = __shfl(d, lane | 15, 64);
            va[reg] = dd * a0[reg];
            vb[reg] = (r16 == 15) ? tv : dd * a1[reg];
        }
        uint2 pa, pb;
        pa.x = pk2(va[0], va[1]); pa.y = pk2(va[2], va[3]);
        pb.x = pk2(vb[0], vb[1]); pb.y = pk2(vb[2], vb[3]);
        *reinterpret_cast<uint2*>(&dst[r16 * ST + row0 + 4 * g])        = pa;
        *reinterpret_cast<uint2*>(&dst[(16 + r16) * ST + row0 + 4 * g]) = pb;
    };

    for (int pass = 0; pass < NPASS; ++pass) {
        const int pbase = blockIdx.x * PPB + pass * PB;

        // ---- publish x (prefetch regs -> xb) ----
        if (act) xb[pl0][c0] = (c0 < 31) ? pf : force;
        __syncthreads();  // [E] xb ready; prev-pass XT[0] reads done

        // ---- layer 0: Z0 = W0 @ [I|x] -> XT[0] (MFMA, conflict-free epi) ----
        {
            float xa[8];
            const float4* xp = reinterpret_cast<const float4*>(&xb[pt][g * 8]);
            float4 x0 = xp[0], x1 = xp[1];
            xa[0]=x0.x; xa[1]=x0.y; xa[2]=x0.z; xa[3]=x0.w;
            xa[4]=x1.x; xa[5]=x1.y; xa[6]=x1.z; xa[7]=x1.w;
            short8 xpk = pack8f(xa);
            short8 bf0 = oh0;
            short8 bf1 = (r16 == 15) ? xpk : oh1;
            f32x4 a00 = {0.f,0.f,0.f,0.f}, a01 = {0.f,0.f,0.f,0.f};
            f32x4 a10 = {0.f,0.f,0.f,0.f}, a11 = {0.f,0.f,0.f,0.f};
            __builtin_amdgcn_s_setprio(1);
            a00 = __builtin_amdgcn_mfma_f32_16x16x32_bf16(aW0[0], bf0, a00, 0, 0, 0);
            a01 = __builtin_amdgcn_mfma_f32_16x16x32_bf16(aW0[0], bf1, a01, 0, 0, 0);
            a10 = __builtin_amdgcn_mfma_f32_16x16x32_bf16(aW0[1], bf0, a10, 0, 0, 0);
            a11 = __builtin_amdgcn_mfma_f32_16x16x32_bf16(aW0[1], bf1, a11, 0, 0, 0);
            __builtin_amdgcn_s_setprio(0);
            epi(a00, a01, 0, bbf[0], &XT[0][pt][0][0]);
            epi(a10, a11, 1, bbf[0], &XT[0][pt][0][0]);
        }

        // ---- y prefetch for next pass (hides under L1-L3) ----
        if (act && c0 < 31 && pass + 1 < NPASS)
            pf = y[(size_t)(pbase + PB + pl0) * 31 + c0];

        __syncthreads();  // [A] X0 ready

        // ---- layers 1, 2: XT[L] -> XT[1-L]; paired m-tiles ----
        #pragma unroll
        for (int L = 0; L < 2; ++L) {
            f32x4 acc[2][2] = {{{0.f,0.f,0.f,0.f},{0.f,0.f,0.f,0.f}},
                               {{0.f,0.f,0.f,0.f},{0.f,0.f,0.f,0.f}}};
            __builtin_amdgcn_s_setprio(1);
            #pragma unroll
            for (int kc = 0; kc < 4; ++kc) {
                short8 bf0 = *reinterpret_cast<const short8*>(&XT[L][pt][r16][kc * 32 + g * 8]);
                short8 bf1 = *reinterpret_cast<const short8*>(&XT[L][pt][16 + r16][kc * 32 + g * 8]);
                acc[0][0] = __builtin_amdgcn_mfma_f32_16x16x32_bf16(aW[L][0][kc], bf0, acc[0][0], 0, 0, 0);
                acc[0][1] = __builtin_amdgcn_mfma_f32_16x16x32_bf16(aW[L][0][kc], bf1, acc[0][1], 0, 0, 0);
                acc[1][0] = __builtin_amdgcn_mfma_f32_16x16x32_bf16(aW[L][1][kc], bf0, acc[1][0], 0, 0, 0);
                acc[1][1] = __builtin_amdgcn_mfma_f32_16x16x32_bf16(aW[L][1][kc], bf1, acc[1][1], 0, 0, 0);
            }
            __builtin_amdgcn_s_setprio(0);
            epi(acc[0][0], acc[0][1], 0, bbf[L + 1], &XT[1 - L][pt][0][0]);
            epi(acc[1][0], acc[1][1], 1, bbf[L + 1], &XT[1 - L][pt][0][0]);
            __syncthreads();  // [B]/[C]
        }

        // ---- layer 3: wave (mw,nw,pt); W3 frags from LDS; direct scatter ----
        {
            uint2 b3q = *reinterpret_cast<const uint2*>(&b3L[16 * mw + 4 * g]);
            const ushort* b3s = reinterpret_cast<const ushort*>(&b3q);
            f32x4 a = {0.f, 0.f, 0.f, 0.f};
            __builtin_amdgcn_s_setprio(1);
            #pragma unroll
            for (int kc = 0; kc < 4; ++kc) {
                short8 aw3 = *reinterpret_cast<const short8*>(&W3L[(16 * mw + r16) * ST3 + kc * 32 + g * 8]);
                short8 bf  = *reinterpret_cast<const short8*>(&XT[0][pt][16 * nw + r16][kc * 32 + g * 8]);
                a = __builtin_amdgcn_mfma_f32_16x16x32_bf16(aw3, bf, a, 0, 0, 0);
            }
            __builtin_amdgcn_s_setprio(0);
            const size_t p = (size_t)(pbase + pt);
            const int c = 16 * nw + r16;
            if ((int)p < npts) {
                #pragma unroll
                for (int reg = 0; reg < 4; ++reg) {
                    const int o = 16 * mw + 4 * g + reg;
                    if (o < 31) {
                        if (c == 31) out[p * 31 + o] = a[reg] + bf2f(b3s[reg]);
                        else         jac[(p * 31 + o) * 31 + c] = a[reg];
                    }
                }
            }
        }
        // no barrier: loop-top [E] separates XT[0] reads from next L0 writes
    }
}

extern "C" void kernel_launch(void* const* d_in, const int* in_sizes, int n_in,
                              void* d_out, int out_size, void* d_ws, size_t ws_size,
                              hipStream_t stream) {
    const float* t  = (const float*)d_in[0];
    const float* y  = (const float*)d_in[1];
    const float* W0 = (const float*)d_in[2];
    const float* b0 = (const float*)d_in[3];
    const float* W1 = (const float*)d_in[4];
    const float* b1 = (const float*)d_in[5];
    const float* W2 = (const float*)d_in[6];
    const float* b2 = (const float*)d_in[7];
    const float* W3 = (const float*)d_in[8];
    const float* b3 = (const float*)d_in[9];

    const int npts = in_sizes[1] / 31;  // 65536
    float* out = (float*)d_out;
    float* jac = out + (size_t)npts * 31;

    const int blocks = (npts + PPB - 1) / PPB;  // 4096
    node_mfma<<<blocks, 512, 0, stream>>>(t, y, W0, b0, W1, b1, W2, b2, W3, b3,
                                          out, jac, npts);
}

// Round 10
// 332.132 us; speedup vs baseline: 1.5314x; 1.5314x over previous
//
#include <hip/hip_runtime.h>
#include <hip/hip_bf16.h>
#include <math.h>

// N_IN=32, N_OUT=31, H=128, npts=65536.
// Per point: X_l (128x32) propagated through Z = W_l @ X, with
// X'[:, :31] = D * Z[:, :31], X'[:, 31] = tanh(Z[:,31] + b).
// MFMA 16x16x32 bf16. Round-5 shell (512 thr, PB=4, ping-pong XT,
// 4 barriers/pass, y prefetch, direct scatter) with ONE change:
// layer 0 runs as MFMA on [I_31 | x] (one-hot register B-frags), writing
// X0 through the same conflict-free uint2 epilogue as L1/L2 — removes the
// 8-way-conflicted scalar ushort writes and the L0 VALU dot/reduce.

using short8 = __attribute__((ext_vector_type(8))) short;
using f32x4  = __attribute__((ext_vector_type(4))) float;

#define PB 4          // points per pass
#define PPB 32        // points per block
#define STRIDE 136    // ushort elems per XT row (272 B = 17*16: 16B-aligned rows)

__device__ __forceinline__ float fast_tanh(float z) {
    float e = __expf(2.0f * z);
    return 1.0f - 2.0f * __builtin_amdgcn_rcpf(e + 1.0f);
}

// pack 2 f32 -> 1 dword of 2 bf16 (v_cvt_pk_bf16_f32; no builtin on gfx950)
__device__ __forceinline__ unsigned pk2(float lo, float hi) {
    unsigned r;
    asm("v_cvt_pk_bf16_f32 %0, %1, %2" : "=v"(r) : "v"(lo), "v"(hi));
    return r;
}

__device__ __forceinline__ short8 pack8f(const float* s) {
    union { unsigned u[4]; short8 v; } r;
    #pragma unroll
    for (int qq = 0; qq < 4; ++qq) r.u[qq] = pk2(s[2 * qq], s[2 * qq + 1]);
    return r.v;
}

__device__ __forceinline__ short8 load_row8(const float* p) {
    float tmp[8];
    const float4* p4 = reinterpret_cast<const float4*>(p);
    float4 q0 = p4[0], q1 = p4[1];
    tmp[0]=q0.x; tmp[1]=q0.y; tmp[2]=q0.z; tmp[3]=q0.w;
    tmp[4]=q1.x; tmp[5]=q1.y; tmp[6]=q1.z; tmp[7]=q1.w;
    return pack8f(tmp);
}

__global__ void __launch_bounds__(512, 4)
node_mfma(const float* __restrict__ tptr,
          const float* __restrict__ y,
          const float* __restrict__ W0, const float* __restrict__ b0,
          const float* __restrict__ W1, const float* __restrict__ b1,
          const float* __restrict__ W2, const float* __restrict__ b2,
          const float* __restrict__ W3, const float* __restrict__ b3,
          float* __restrict__ out, float* __restrict__ jac, int npts) {
    // XT[buf][point][col c][row j]; buf0 holds X0/X2, buf1 holds X1
    __shared__ __align__(16) ushort XT[2][PB][32][STRIDE];
    __shared__ __align__(16) float xb[PB][32];

    const int tid  = threadIdx.x;
    const int w    = tid >> 6;
    const int lane = tid & 63;
    const int r16  = lane & 15;   // A-row / B-col / D-col within tile
    const int g    = lane >> 4;   // k-octet group; D rows = 4g..4g+3
    const int j    = 16 * w + r16;  // this wave's m-tile rows (all layers 0-2)

    // ---- weights -> registers ----
    short8 aW0 = load_row8(W0 + j * 32 + g * 8);  // W0 A-frag (K=32, one kc)
    short8 aW[2][4];  // A-frags W1, W2: lane holds row j, k = kc*32 + g*8 + i
    #pragma unroll
    for (int kc = 0; kc < 4; ++kc) {
        aW[0][kc] = load_row8(W1 + j * 128 + kc * 32 + g * 8);
        aW[1][kc] = load_row8(W2 + j * 128 + kc * 32 + g * 8);
    }
    // layer 3 (padded to 32 rows): wave w -> (m=(w>>1)&1, n=w&1), points (w>>2)+{0,2}
    const int mw = (w >> 1) & 1, nw = w & 1;
    const int r3 = 16 * mw + r16;
    short8 aW3[4];
    #pragma unroll
    for (int kc = 0; kc < 4; ++kc) {
        if (r3 < 31) aW3[kc] = load_row8(W3 + r3 * 128 + kc * 32 + g * 8);
        else { short8 z = {0,0,0,0,0,0,0,0}; aW3[kc] = z; }
    }

    // ---- one-hot B-frags for the identity columns of [I|x] ----
    // B elem i of lane (r16,g) is k = g*8+i; bf0 col = r16, bf1 col = 16+r16.
    short8 oh0, oh1;
    {
        union { ushort u[8]; short8 v; } z0, z1;
        #pragma unroll
        for (int i = 0; i < 8; ++i) {
            z0.u[i] = (g == (r16 >> 3) && i == (r16 & 7)) ? (ushort)0x3F80 : (ushort)0;
            z1.u[i] = (r16 < 15 && g == ((16 + r16) >> 3) && i == ((16 + r16) & 7))
                          ? (ushort)0x3F80 : (ushort)0;
        }
        oh0 = z0.v; oh1 = z1.v;
    }

    // ---- biases (f32 regs, per this lane's D rows 16w+4g..+3) ----
    float bv0[4], bv[2][4], b3v[4];
    #pragma unroll
    for (int reg = 0; reg < 4; ++reg) {
        bv0[reg]   = b0[16 * w + 4 * g + reg];
        bv[0][reg] = b1[16 * w + 4 * g + reg];
        bv[1][reg] = b2[16 * w + 4 * g + reg];
        int o = 16 * mw + 4 * g + reg;
        b3v[reg] = (o < 31) ? b3[o] : 0.0f;
    }
    const float force = sinf(tptr[0]);

    // ---- shared epilogue: Z cols -> X' (D-scaled cols + tanh col) ----
    auto epi = [&](f32x4 a0, f32x4 a1, const float* bL4, ushort* dst) {
        float va[4], vb[4];
        #pragma unroll
        for (int reg = 0; reg < 4; ++reg) {
            float tv = fast_tanh(a1[reg] + bL4[reg]);
            float d  = 1.0f - tv * tv;
            float dd = __shfl(d, lane | 15, 64);
            va[reg] = dd * a0[reg];
            vb[reg] = (r16 == 15) ? tv : dd * a1[reg];
        }
        uint2 pa, pb;
        pa.x = pk2(va[0], va[1]); pa.y = pk2(va[2], va[3]);
        pb.x = pk2(vb[0], vb[1]); pb.y = pk2(vb[2], vb[3]);
        *reinterpret_cast<uint2*>(&dst[r16 * STRIDE + 16 * w + 4 * g])        = pa;
        *reinterpret_cast<uint2*>(&dst[(16 + r16) * STRIDE + 16 * w + 4 * g]) = pb;
    };

    // ---- y prefetch for pass 0 ----
    const int pl0 = tid >> 5, c0 = tid & 31;
    const bool act = tid < PB * 32;
    float pf = 0.0f;
    if (act && c0 < 31) pf = y[(size_t)(blockIdx.x * PPB + pl0) * 31 + c0];

    for (int pass = 0; pass < PPB / PB; ++pass) {
        const int pbase = blockIdx.x * PPB + pass * PB;

        // ---- publish x for this pass (from prefetch regs) ----
        if (act) xb[pl0][c0] = (c0 < 31) ? pf : force;
        __syncthreads();  // [E] xb ready; prev-pass XT[0] reads done

        // ---- layer 0: Z0 = W0 @ [I|x] -> XT[0] via MFMA + conflict-free epi ----
        #pragma unroll
        for (int pl = 0; pl < PB; ++pl) {
            float xa[8];
            const float4* xp = reinterpret_cast<const float4*>(&xb[pl][g * 8]);
            float4 x0 = xp[0], x1 = xp[1];
            xa[0]=x0.x; xa[1]=x0.y; xa[2]=x0.z; xa[3]=x0.w;
            xa[4]=x1.x; xa[5]=x1.y; xa[6]=x1.z; xa[7]=x1.w;
            short8 xpk = pack8f(xa);
            short8 bf1 = (r16 == 15) ? xpk : oh1;
            f32x4 a0 = {0.f,0.f,0.f,0.f}, a1 = {0.f,0.f,0.f,0.f};
            __builtin_amdgcn_s_setprio(1);
            a0 = __builtin_amdgcn_mfma_f32_16x16x32_bf16(aW0, oh0, a0, 0, 0, 0);
            a1 = __builtin_amdgcn_mfma_f32_16x16x32_bf16(aW0, bf1, a1, 0, 0, 0);
            __builtin_amdgcn_s_setprio(0);
            epi(a0, a1, bv0, &XT[0][pl][0][0]);
        }

        // ---- issue y prefetch for next pass (hides under layers 1-3) ----
        if (act && c0 < 31 && pass + 1 < PPB / PB)
            pf = y[(size_t)(pbase + PB + pl0) * 31 + c0];

        __syncthreads();  // [A] X0 ready

        // ---- layers 1, 2: src XT[L] -> dst XT[1-L] ----
        #pragma unroll
        for (int L = 0; L < 2; ++L) {
            #pragma unroll
            for (int pl = 0; pl < PB; ++pl) {
                f32x4 a0 = {0.f, 0.f, 0.f, 0.f}, a1 = {0.f, 0.f, 0.f, 0.f};
                __builtin_amdgcn_s_setprio(1);
                #pragma unroll
                for (int kc = 0; kc < 4; ++kc) {
                    short8 bf0 = *reinterpret_cast<const short8*>(&XT[L][pl][r16][kc * 32 + g * 8]);
                    short8 bf1 = *reinterpret_cast<const short8*>(&XT[L][pl][16 + r16][kc * 32 + g * 8]);
                    a0 = __builtin_amdgcn_mfma_f32_16x16x32_bf16(aW[L][kc], bf0, a0, 0, 0, 0);
                    a1 = __builtin_amdgcn_mfma_f32_16x16x32_bf16(aW[L][kc], bf1, a1, 0, 0, 0);
                }
                __builtin_amdgcn_s_setprio(0);
                epi(a0, a1, bv[L], &XT[1 - L][pl][0][0]);
            }
            __syncthreads();  // [B]/[C] X_{L+1} ready
        }

        // ---- layer 3: Y = W3pad @ X2 (X2 in XT[0]); direct scatter stores ----
        #pragma unroll
        for (int tsk = 0; tsk < 2; ++tsk) {
            int pl = (w >> 2) + tsk * 2;
            f32x4 a = {0.f, 0.f, 0.f, 0.f};
            __builtin_amdgcn_s_setprio(1);
            #pragma unroll
            for (int kc = 0; kc < 4; ++kc) {
                short8 bf = *reinterpret_cast<const short8*>(&XT[0][pl][16 * nw + r16][kc * 32 + g * 8]);
                a = __builtin_amdgcn_mfma_f32_16x16x32_bf16(aW3[kc], bf, a, 0, 0, 0);
            }
            __builtin_amdgcn_s_setprio(0);
            size_t p = (size_t)(pbase + pl);
            int c = 16 * nw + r16;
            if ((int)p < npts) {
                #pragma unroll
                for (int reg = 0; reg < 4; ++reg) {
                    int o = 16 * mw + 4 * g + reg;
                    if (o < 31) {
                        if (c == 31) out[p * 31 + o] = a[reg] + b3v[reg];
                        else         jac[(p * 31 + o) * 31 + c] = a[reg];
                    }
                }
            }
        }
        // no barrier here: loop-top [E] separates XT[0] reads from next L0 writes
    }
}

extern "C" void kernel_launch(void* const* d_in, const int* in_sizes, int n_in,
                              void* d_out, int out_size, void* d_ws, size_t ws_size,
                              hipStream_t stream) {
    const float* t  = (const float*)d_in[0];
    const float* y  = (const float*)d_in[1];
    const float* W0 = (const float*)d_in[2];
    const float* b0 = (const float*)d_in[3];
    const float* W1 = (const float*)d_in[4];
    const float* b1 = (const float*)d_in[5];
    const float* W2 = (const float*)d_in[6];
    const float* b2 = (const float*)d_in[7];
    const float* W3 = (const float*)d_in[8];
    const float* b3 = (const float*)d_in[9];

    const int npts = in_sizes[1] / 31;  // 65536
    float* out = (float*)d_out;
    float* jac = out + (size_t)npts * 31;

    const int blocks = (npts + PPB - 1) / PPB;  // 2048
    node_mfma<<<blocks, 512, 0, stream>>>(t, y, W0, b0, W1, b1, W2, b2, W3, b3,
                                          out, jac, npts);
}